// Round 5
// baseline (163.550 us; speedup 1.0000x reference)
//
#include <hip/hip_runtime.h>
#include <hip/hip_bf16.h>

// VQ-VAE quantize: x[32,64,64,64] NCHW fp32, codebook[512,64] fp32.
// out[0] = 1.25*SSD/8388608 ; out[1..] = codebook[argmin] in NCHW.
// R5: prep kernel pre-converts codebook to bf16 MFMA-fragment layout + hn2
// (removes per-block convert/hn2 redundancy). Main kernel: 128-row tiles,
// 4 blocks/CU, quarters staged via 4 uint4 L2 loads (short-lived regs only -
// cross-barrier reg prefetch spills to scratch, see R2/R3). Phase-B uses
// [64][132] d-major LDS overlay: linear b128 reads -> float4 NCHW stores.
// Loss fused: SSD = sum(x^2) - 2*sum(best score), score = dot - ||c||^2/2.

typedef __attribute__((ext_vector_type(8))) __bf16 bf16x8;
typedef __attribute__((ext_vector_type(4))) float f32x4;

// ---- d_ws layout (bytes) ----
#define WS_CBF   0        // 65536: bf16 codebook B-fragments (32 ct x 2 kk x 1KB)
#define WS_HN2   65536    // 2048:  -0.5*||c||^2 f32[512]
#define WS_RED   67584    // 4096:  per-block loss partials f32[1024]

// ---- k1 LDS layout (bytes) ----
#define K_XA   0        // 16384: bf16 x-tile [128 rows][64 d] swizzled
#define K_CB   16384    // 16384: codebook quarter, fragment-linear
#define K_HN   32768    // 2048:  hn2 f32[512]
#define K_IDX  34816    // 512:   int idx[128]
#define K_RED  35328    // 16
#define K_SZ   35344
// phase-B overlay: f32 qld2[64][132] = 33792 B over [0, 33792) (xa/cb/hn dead)

__device__ __forceinline__ unsigned f2b1(float f) {
  unsigned u = __float_as_uint(f);
  return (u + 0x7FFFu + ((u >> 16) & 1)) >> 16;   // RNE float->bf16 bits
}
__device__ __forceinline__ unsigned pack2(float lo, float hi) {
  return f2b1(lo) | (f2b1(hi) << 16);
}
__device__ __forceinline__ int swz(int row) {    // XOR swizzle, 16B granules
  return ((row & 7) ^ ((row >> 4) & 7)) << 4;
}

// ================= k0: codebook -> fragment layout + hn2 =================
__global__ void vq_prep(const float* __restrict__ cb, char* __restrict__ ws) {
  const int n = blockIdx.x * 64 + threadIdx.x;    // code 0..511
  const float4* cb4 = (const float4*)cb;
  float4 f[16];
  #pragma unroll
  for (int j = 0; j < 16; ++j) f[j] = cb4[(n << 4) + j];
  float s = 0.f;
  #pragma unroll
  for (int j = 0; j < 16; ++j)
    s += f[j].x * f[j].x + f[j].y * f[j].y + f[j].z * f[j].z + f[j].w * f[j].w;
  ((float*)(ws + WS_HN2))[n] = -0.5f * s;
  const int ct = n >> 4, col = n & 15;
  // B-fragment: lane = (g<<4)|col holds code ct*16+col, k = kk*32+g*8+e
  #pragma unroll
  for (int kk = 0; kk < 2; ++kk) {
    #pragma unroll
    for (int g = 0; g < 4; ++g) {
      float4 a = f[kk * 8 + g * 2], b = f[kk * 8 + g * 2 + 1];
      uint4 u = {pack2(a.x, a.y), pack2(a.z, a.w), pack2(b.x, b.y), pack2(b.z, b.w)};
      *(uint4*)(ws + WS_CBF + (((ct << 1) + kk) << 10) + (((g << 4) | col) << 4)) = u;
    }
  }
}

// ================= k1: argmin + loss + scatter =================
__global__ void __launch_bounds__(256, 4)
vq_main(const float* __restrict__ x, const float* __restrict__ cb,
        const char* __restrict__ wsr, float* __restrict__ out,
        float* __restrict__ wsw) {
  __shared__ __align__(16) char smem[K_SZ];
  char*  xaz  = smem + K_XA;
  char*  cbq  = smem + K_CB;
  float* hn2z = (float*)(smem + K_HN);
  int*   idxz = (int*)(smem + K_IDX);
  float* redz = (float*)(smem + K_RED);
  float* qld2 = (float*)smem;             // phase-B overlay [64][132]

  const int t    = threadIdx.x;
  const int bid  = blockIdx.x;
  const int bimg = bid >> 5;
  const int hw0  = (bid & 31) << 7;
  const float4* xb4 = (const float4*)(x + (bimg << 18) + hw0);
  const float4* cb4 = (const float4*)cb;
  const uint4*  cbf = (const uint4*)(wsr + WS_CBF);

  // ---- stage codebook quarter 0 (load -> ds_write, short-lived) ----
  #pragma unroll
  for (int i = 0; i < 4; ++i) {
    uint4 u = cbf[(i << 8) + t];
    *(uint4*)(cbq + (((i << 8) + t) << 4)) = u;
  }
  // ---- stage X tile: bf16 [row][d] swizzled + sum x^2 ----
  float xsq = 0.f;
  {
    const int p  = t >> 3;                // d-pair 0..31
    const int r0 = (t & 7) << 4;          // row group
    #pragma unroll
    for (int j = 0; j < 4; ++j) {
      float4 A0 = xb4[((2 * p) << 10) + (r0 >> 2) + j];
      float4 A1 = xb4[((2 * p + 1) << 10) + (r0 >> 2) + j];
      const float* a0 = (const float*)&A0;
      const float* a1 = (const float*)&A1;
      #pragma unroll
      for (int u = 0; u < 4; ++u) {
        xsq = fmaf(a0[u], a0[u], xsq);
        xsq = fmaf(a1[u], a1[u], xsq);
        int r = r0 + (j << 2) + u;
        *(unsigned*)(xaz + r * 128 + ((p << 2) ^ swz(r))) = pack2(a0[u], a1[u]);
      }
    }
  }
  // ---- hn2 from prep ----
  hn2z[t]       = ((const float*)(wsr + WS_HN2))[t];
  hn2z[t + 256] = ((const float*)(wsr + WS_HN2))[t + 256];
  __syncthreads();

  const int lane = t & 63;
  const int wid  = t >> 6;
  const int lrow = lane & 15;
  const int lk2  = (lane >> 4) << 4;

  // A fragments persist in regs (2 row-subtiles x 2 k-steps)
  bf16x8 af[2][2];
  #pragma unroll
  for (int s = 0; s < 2; ++s) {
    int row = (wid << 5) + (s << 4) + lrow;
    int sw = swz(row);
    af[s][0] = *(const bf16x8*)(xaz + row * 128 + (lk2 ^ sw));
    af[s][1] = *(const bf16x8*)(xaz + row * 128 + ((lk2 ^ 64) ^ sw));
  }

  float bestv[2][4];
  int   besti[2][4];
  #pragma unroll
  for (int s = 0; s < 2; ++s)
    #pragma unroll
    for (int r = 0; r < 4; ++r) { bestv[s][r] = -3.0e38f; besti[s][r] = 0; }

  for (int q = 0; q < 4; ++q) {
    #pragma unroll
    for (int c8 = 0; c8 < 8; ++c8) {
      const bf16x8 b0 = *(const bf16x8*)(cbq + (c8 << 11) + (lane << 4));
      const bf16x8 b1 = *(const bf16x8*)(cbq + (c8 << 11) + 1024 + (lane << 4));
      const int nc = (q << 7) + (c8 << 4) + lrow;
      const float hv = hn2z[nc];
      #pragma unroll
      for (int s = 0; s < 2; ++s) {
        f32x4 acc = {hv, hv, hv, hv};
        acc = __builtin_amdgcn_mfma_f32_16x16x32_bf16(af[s][0], b0, acc, 0, 0, 0);
        acc = __builtin_amdgcn_mfma_f32_16x16x32_bf16(af[s][1], b1, acc, 0, 0, 0);
        #pragma unroll
        for (int r = 0; r < 4; ++r) {
          if (acc[r] > bestv[s][r]) { bestv[s][r] = acc[r]; besti[s][r] = nc; }
        }
      }
    }
    if (q < 3) {
      __syncthreads();                 // all waves done reading this quarter
      #pragma unroll
      for (int i = 0; i < 4; ++i) {    // short-lived: L2 load -> ds_write
        uint4 u = cbf[(((q + 1) << 10)) + (i << 8) + t];
        *(uint4*)(cbq + (((i << 8) + t) << 4)) = u;
      }
      __syncthreads();
    }
  }

  // ---- cross-lane argmax over the 16 code columns + loss partial ----
  float vsum = 0.f;
  #pragma unroll
  for (int s = 0; s < 2; ++s) {
    #pragma unroll
    for (int r = 0; r < 4; ++r) {
      float v = bestv[s][r];
      int  id = besti[s][r];
      #pragma unroll
      for (int m = 1; m <= 8; m <<= 1) {
        float pv = __shfl_xor(v, m, 64);
        int   pi = __shfl_xor(id, m, 64);
        if (pv > v || (pv == v && pi < id)) { v = pv; id = pi; }
      }
      if (lrow == 0) {
        idxz[(wid << 5) + (s << 4) + ((lane >> 4) << 2) + r] = id;
        vsum += v;
      }
    }
  }
  float lacc = xsq - 2.0f * vsum;
  #pragma unroll
  for (int m = 32; m; m >>= 1) lacc += __shfl_xor(lacc, m, 64);
  if (lane == 0) redz[wid] = lacc;
  __syncthreads();                      // idx+red ready; xaz/cbq/hn now dead
  if (t == 0) wsw[bid] = redz[0] + redz[1] + redz[2] + redz[3];

  // ---- phase B: gather code rows -> d-major LDS -> float4 NCHW store ----
  {
    const int myrow = t >> 1;           // 0..127
    const int chh   = t & 1;            // d-half
    const int myidx = idxz[myrow];
    const float4* cbr = cb4 + (myidx << 4) + (chh << 3);
    #pragma unroll
    for (int j = 0; j < 8; ++j) {
      float4 v = cbr[j];
      const int d = (chh << 5) + (j << 2);
      qld2[(d + 0) * 132 + myrow] = v.x;
      qld2[(d + 1) * 132 + myrow] = v.y;
      qld2[(d + 2) * 132 + myrow] = v.z;
      qld2[(d + 3) * 132 + myrow] = v.w;
    }
  }
  __syncthreads();
  {
    float* outq = out + 1 + (bimg << 18) + hw0;
    const int r4 = (t & 31) << 2;       // row group of 4 (float4)
    const int d0 = t >> 5;              // base d (0..7)
    #pragma unroll
    for (int i = 0; i < 8; ++i) {
      const int d = d0 + (i << 3);
      float4 v = *(const float4*)(qld2 + d * 132 + r4);   // linear b128
      *(float4*)(outq + (d << 12) + r4) = v;              // coalesced 16B
    }
  }
}

__global__ void vq_finalize(const float* __restrict__ ws, float* __restrict__ out) {
  int t = threadIdx.x;
  __shared__ float red[4];
  const float* r = ws;
  float v = r[t] + r[t + 256] + r[t + 512] + r[t + 768];
  #pragma unroll
  for (int m = 32; m; m >>= 1) v += __shfl_xor(v, m, 64);
  if ((t & 63) == 0) red[t >> 6] = v;
  __syncthreads();
  if (t == 0) out[0] = (red[0] + red[1] + red[2] + red[3]) * (1.25f / 8388608.0f);
}

extern "C" void kernel_launch(void* const* d_in, const int* in_sizes, int n_in,
                              void* d_out, int out_size, void* d_ws, size_t ws_size,
                              hipStream_t stream) {
  const float* x  = (const float*)d_in[0];   // 32*64*64*64 fp32 NCHW
  const float* cb = (const float*)d_in[1];   // 512*64 fp32
  float* out = (float*)d_out;                // [0]=loss, [1..]=quantized NCHW
  char*  ws  = (char*)d_ws;                  // ~72 KB used
  vq_prep<<<8, 64, 0, stream>>>(cb, ws);
  vq_main<<<1024, 256, 0, stream>>>(x, cb, ws, out, (float*)(ws + WS_RED));
  vq_finalize<<<1, 256, 0, stream>>>((float*)(ws + WS_RED), out);
}

// Round 6
// 38.284 us; speedup vs baseline: 4.2720x; 4.2720x over previous
//
#include <hip/hip_runtime.h>
#include <hip/hip_bf16.h>

// VQ-VAE quantize: x[32,64,64,64] NCHW fp32, codebook[512,64] fp32.
// out[0] = 1.25*SSD/8388608 ; out[1..] = codebook[argmin] in NCHW.
// R6: NO codebook LDS staging (R2/R3/R5 all died on compiler scratch-spill
// around staged-load patterns). B-fragments read directly from L2-resident
// d_ws (prep-converted bf16 MFMA layout), unroll-2 bounded. No mid-loop
// barriers. x-tile LDS transpose (proven R1/R4) + fused loss
// SSD = sum(x^2) - 2*sum(best score), score = dot - ||c||^2/2.

typedef __attribute__((ext_vector_type(8))) __bf16 bf16x8;
typedef __attribute__((ext_vector_type(4))) float f32x4;

// ---- d_ws layout (bytes) ----
#define WS_CBF   0        // 65536: bf16 codebook B-fragments (32 ct x 2 kk x 1KB)
#define WS_HN2   65536    // 2048:  -0.5*||c||^2 f32[512]
#define WS_RED   67584    // 4096:  per-block loss partials f32[1024]

// ---- main kernel LDS layout (bytes) ----
#define K_XA   0        // 16384: bf16 x-tile [128 rows][64 d] swizzled
#define K_HN   16384    // 2048:  hn2 f32[512]
#define K_IDX  33792    // 512:   int idx[128]   (outside phase-B overlay)
#define K_RED  34304    // 16
#define K_SZ   34320
// phase-B overlay: f32 qld2[64][132] = 33792 B over [0, 33792); xa/hn dead.

__device__ __forceinline__ unsigned f2b1(float f) {
  unsigned u = __float_as_uint(f);
  return (u + 0x7FFFu + ((u >> 16) & 1)) >> 16;   // RNE float->bf16 bits
}
__device__ __forceinline__ unsigned pack2(float lo, float hi) {
  return f2b1(lo) | (f2b1(hi) << 16);
}
__device__ __forceinline__ int swz(int row) {    // XOR swizzle, 16B granules
  return ((row & 7) ^ ((row >> 4) & 7)) << 4;
}

// ================= k0: codebook -> fragment layout + hn2 =================
__global__ void vq_prep(const float* __restrict__ cb, char* __restrict__ ws) {
  const int n = blockIdx.x * 64 + threadIdx.x;    // code 0..511
  const float4* cb4 = (const float4*)cb;
  float4 f[16];
  #pragma unroll
  for (int j = 0; j < 16; ++j) f[j] = cb4[(n << 4) + j];
  float s = 0.f;
  #pragma unroll
  for (int j = 0; j < 16; ++j)
    s += f[j].x * f[j].x + f[j].y * f[j].y + f[j].z * f[j].z + f[j].w * f[j].w;
  ((float*)(ws + WS_HN2))[n] = -0.5f * s;
  const int ct = n >> 4, col = n & 15;
  // B-fragment: lane = (g<<4)|col holds code ct*16+col, k = kk*32+g*8+e
  #pragma unroll
  for (int kk = 0; kk < 2; ++kk) {
    #pragma unroll
    for (int g = 0; g < 4; ++g) {
      float4 a = f[kk * 8 + g * 2], b = f[kk * 8 + g * 2 + 1];
      uint4 u = {pack2(a.x, a.y), pack2(a.z, a.w), pack2(b.x, b.y), pack2(b.z, b.w)};
      *(uint4*)(ws + WS_CBF + (((ct << 1) + kk) << 10) + (((g << 4) | col) << 4)) = u;
    }
  }
}

// ================= k1: argmin + loss + scatter =================
__global__ void __launch_bounds__(256, 4)
vq_main(const float* __restrict__ x, const float* __restrict__ cb,
        const char* __restrict__ wsr, float* __restrict__ out,
        float* __restrict__ wsw) {
  __shared__ __align__(16) char smem[K_SZ];
  char*  xaz  = smem + K_XA;
  float* hn2z = (float*)(smem + K_HN);
  int*   idxz = (int*)(smem + K_IDX);
  float* redz = (float*)(smem + K_RED);
  float* qld2 = (float*)smem;             // phase-B overlay [64][132]

  const int t    = threadIdx.x;
  const int bid  = blockIdx.x;
  const int bimg = bid >> 5;
  const int hw0  = (bid & 31) << 7;
  const float4*  xb4 = (const float4*)(x + (bimg << 18) + hw0);
  const float4*  cb4 = (const float4*)cb;
  const bf16x8*  cbb = (const bf16x8*)(wsr + WS_CBF);   // fragment-linear

  // ---- stage X tile: bf16 [row][d] swizzled + sum x^2 ----
  float xsq = 0.f;
  {
    const int p  = t >> 3;                // d-pair 0..31
    const int r0 = (t & 7) << 4;          // row group
    #pragma unroll
    for (int j = 0; j < 4; ++j) {
      float4 A0 = xb4[((2 * p) << 10) + (r0 >> 2) + j];
      float4 A1 = xb4[((2 * p + 1) << 10) + (r0 >> 2) + j];
      const float* a0 = (const float*)&A0;
      const float* a1 = (const float*)&A1;
      #pragma unroll
      for (int u = 0; u < 4; ++u) {
        xsq = fmaf(a0[u], a0[u], xsq);
        xsq = fmaf(a1[u], a1[u], xsq);
        int r = r0 + (j << 2) + u;
        *(unsigned*)(xaz + r * 128 + ((p << 2) ^ swz(r))) = pack2(a0[u], a1[u]);
      }
    }
  }
  // ---- hn2 from prep (tiny) ----
  hn2z[t]       = ((const float*)(wsr + WS_HN2))[t];
  hn2z[t + 256] = ((const float*)(wsr + WS_HN2))[t + 256];
  __syncthreads();

  const int lane = t & 63;
  const int wid  = t >> 6;
  const int lrow = lane & 15;
  const int lk2  = (lane >> 4) << 4;

  // A fragments persist in regs (2 row-subtiles x 2 k-steps)
  bf16x8 af[2][2];
  #pragma unroll
  for (int s = 0; s < 2; ++s) {
    int row = (wid << 5) + (s << 4) + lrow;
    int sw = swz(row);
    af[s][0] = *(const bf16x8*)(xaz + row * 128 + (lk2 ^ sw));
    af[s][1] = *(const bf16x8*)(xaz + row * 128 + ((lk2 ^ 64) ^ sw));
  }

  float bestv[2][4];
  int   besti[2][4];
  #pragma unroll
  for (int s = 0; s < 2; ++s)
    #pragma unroll
    for (int r = 0; r < 4; ++r) { bestv[s][r] = -3.0e38f; besti[s][r] = 0; }

  // ---- main loop: B direct from L2 (no LDS, no barriers) ----
  #pragma unroll 2
  for (int ct = 0; ct < 32; ++ct) {
    const bf16x8 b0 = cbb[(ct << 7) + lane];        // kk=0 fragment
    const bf16x8 b1 = cbb[(ct << 7) + 64 + lane];   // kk=1 fragment
    const int nc = (ct << 4) + lrow;
    const float hv = hn2z[nc];
    #pragma unroll
    for (int s = 0; s < 2; ++s) {
      f32x4 acc = {hv, hv, hv, hv};
      acc = __builtin_amdgcn_mfma_f32_16x16x32_bf16(af[s][0], b0, acc, 0, 0, 0);
      acc = __builtin_amdgcn_mfma_f32_16x16x32_bf16(af[s][1], b1, acc, 0, 0, 0);
      #pragma unroll
      for (int r = 0; r < 4; ++r) {
        if (acc[r] > bestv[s][r]) { bestv[s][r] = acc[r]; besti[s][r] = nc; }
      }
    }
  }

  // ---- cross-lane argmax over the 16 code columns + loss partial ----
  float vsum = 0.f;
  #pragma unroll
  for (int s = 0; s < 2; ++s) {
    #pragma unroll
    for (int r = 0; r < 4; ++r) {
      float v = bestv[s][r];
      int  id = besti[s][r];
      #pragma unroll
      for (int m = 1; m <= 8; m <<= 1) {
        float pv = __shfl_xor(v, m, 64);
        int   pi = __shfl_xor(id, m, 64);
        if (pv > v || (pv == v && pi < id)) { v = pv; id = pi; }
      }
      if (lrow == 0) {
        idxz[(wid << 5) + (s << 4) + ((lane >> 4) << 2) + r] = id;
        vsum += v;
      }
    }
  }
  float lacc = xsq - 2.0f * vsum;
  #pragma unroll
  for (int m = 32; m; m >>= 1) lacc += __shfl_xor(lacc, m, 64);
  if (lane == 0) redz[wid] = lacc;
  __syncthreads();                      // idx+red ready; xa/hn now dead
  if (t == 0) wsw[bid] = redz[0] + redz[1] + redz[2] + redz[3];

  // ---- phase B: gather code rows -> d-major LDS -> float4 NCHW store ----
  {
    const int myrow = t >> 1;           // 0..127
    const int chh   = t & 1;            // d-half
    const int myidx = idxz[myrow];
    const float4* cbr = cb4 + (myidx << 4) + (chh << 3);
    #pragma unroll
    for (int j = 0; j < 8; ++j) {
      float4 v = cbr[j];
      const int d = (chh << 5) + (j << 2);
      qld2[(d + 0) * 132 + myrow] = v.x;
      qld2[(d + 1) * 132 + myrow] = v.y;
      qld2[(d + 2) * 132 + myrow] = v.z;
      qld2[(d + 3) * 132 + myrow] = v.w;
    }
  }
  __syncthreads();
  {
    float* outq = out + 1 + (bimg << 18) + hw0;
    const int r4 = (t & 31) << 2;       // row group of 4 (float4)
    const int d0 = t >> 5;              // base d (0..7)
    #pragma unroll
    for (int i = 0; i < 8; ++i) {
      const int d = d0 + (i << 3);
      float4 v = *(const float4*)(qld2 + d * 132 + r4);   // linear b128
      *(float4*)(outq + (d << 12) + r4) = v;              // coalesced 16B
    }
  }
}

__global__ void vq_finalize(const float* __restrict__ ws, float* __restrict__ out) {
  int t = threadIdx.x;
  __shared__ float red[4];
  float v = ws[t] + ws[t + 256] + ws[t + 512] + ws[t + 768];
  #pragma unroll
  for (int m = 32; m; m >>= 1) v += __shfl_xor(v, m, 64);
  if ((t & 63) == 0) red[t >> 6] = v;
  __syncthreads();
  if (t == 0) out[0] = (red[0] + red[1] + red[2] + red[3]) * (1.25f / 8388608.0f);
}

extern "C" void kernel_launch(void* const* d_in, const int* in_sizes, int n_in,
                              void* d_out, int out_size, void* d_ws, size_t ws_size,
                              hipStream_t stream) {
  const float* x  = (const float*)d_in[0];   // 32*64*64*64 fp32 NCHW
  const float* cb = (const float*)d_in[1];   // 512*64 fp32
  float* out = (float*)d_out;                // [0]=loss, [1..]=quantized NCHW
  char*  ws  = (char*)d_ws;                  // ~72 KB used
  vq_prep<<<8, 64, 0, stream>>>(cb, ws);
  vq_main<<<1024, 256, 0, stream>>>(x, cb, ws, out, (float*)(ws + WS_RED));
  vq_finalize<<<1, 256, 0, stream>>>((float*)(ws + WS_RED), out);
}

// Round 7
// 33.939 us; speedup vs baseline: 4.8189x; 1.1280x over previous
//
#include <hip/hip_runtime.h>
#include <hip/hip_bf16.h>

// VQ-VAE quantize: x[32,64,64,64] NCHW fp32, codebook[512,64] fp32.
// out[0] = 1.25*SSD/8388608 ; out[1..] = codebook[argmin] in NCHW.
// R7: R6 structure (direct-L2 B reads, no mid-loop staging/barriers) +
//  - u32-key argmax: key = (bits(score+1) & ~511) | (511-nc); and_or+max_u32
//  - v_perm truncation pack for x->bf16 staging (1 op vs 5)
//  - 2048 blocks x 128 thr x 64 rows: ~9 blocks/CU for phase overlap
// Loss fused: SSD = sum(x^2) - 2*sum(best score); score decoded from key.

typedef __attribute__((ext_vector_type(8))) __bf16 bf16x8;
typedef __attribute__((ext_vector_type(4))) float f32x4;

// ---- d_ws layout (bytes) ----
#define WS_CBF   0        // 65536: bf16 codebook B-fragments (32 ct x 2 kk x 1KB)
#define WS_HN2   65536    // 2048:  (1.0 - 0.5*||c||^2) f32[512]
#define WS_RED   67584    // 8192:  per-block loss partials f32[2048]

// ---- main kernel LDS layout (bytes) ----
#define K_XA   0        // 8192:  bf16 x-tile [64 rows][64 d] swizzled
#define K_HN   8192     // 2048:  hn2 f32[512]
#define K_IDX  17408    // 256:   int idx[64]   (outside phase-B overlay)
#define K_RED  17664    // 8
#define K_SZ   17680
// phase-B overlay: f32 qld2[64][68] = 17408 B over [0, 17408); xa/hn dead.

__device__ __forceinline__ unsigned f2b1(float f) {
  unsigned u = __float_as_uint(f);
  return (u + 0x7FFFu + ((u >> 16) & 1)) >> 16;   // RNE float->bf16 bits
}
__device__ __forceinline__ unsigned pack2(float lo, float hi) {
  return f2b1(lo) | (f2b1(hi) << 16);
}
#if defined(__has_builtin)
#  if __has_builtin(__builtin_amdgcn_perm)
#    define PACKTR(lo, hi) __builtin_amdgcn_perm(__float_as_uint(hi), \
                             __float_as_uint(lo), 0x07060302u)
#  endif
#endif
#ifndef PACKTR   // fallback: 2-op truncation pack
#  define PACKTR(lo, hi) ((__float_as_uint(hi) & 0xFFFF0000u) | \
                          (__float_as_uint(lo) >> 16))
#endif
__device__ __forceinline__ int swz(int row) {    // XOR swizzle, 16B granules
  return ((row & 7) ^ ((row >> 4) & 7)) << 4;
}

// ================= k0: codebook -> fragment layout + hn2 =================
__global__ void vq_prep(const float* __restrict__ cb, char* __restrict__ ws) {
  const int n = blockIdx.x * 64 + threadIdx.x;    // code 0..511
  const float4* cb4 = (const float4*)cb;
  float4 f[16];
  #pragma unroll
  for (int j = 0; j < 16; ++j) f[j] = cb4[(n << 4) + j];
  float s = 0.f;
  #pragma unroll
  for (int j = 0; j < 16; ++j)
    s += f[j].x * f[j].x + f[j].y * f[j].y + f[j].z * f[j].z + f[j].w * f[j].w;
  ((float*)(ws + WS_HN2))[n] = 1.0f - 0.5f * s;   // +1 shift keeps scores >0
  const int ct = n >> 4, col = n & 15;
  // B-fragment: lane = (g<<4)|col holds code ct*16+col, k = kk*32+g*8+e
  #pragma unroll
  for (int kk = 0; kk < 2; ++kk) {
    #pragma unroll
    for (int g = 0; g < 4; ++g) {
      float4 a = f[kk * 8 + g * 2], b = f[kk * 8 + g * 2 + 1];
      uint4 u = {pack2(a.x, a.y), pack2(a.z, a.w), pack2(b.x, b.y), pack2(b.z, b.w)};
      *(uint4*)(ws + WS_CBF + (((ct << 1) + kk) << 10) + (((g << 4) | col) << 4)) = u;
    }
  }
}

// ================= k1: argmin + loss + scatter =================
__global__ void __launch_bounds__(128, 4)
vq_main(const float* __restrict__ x, const float* __restrict__ cb,
        const char* __restrict__ wsr, float* __restrict__ out,
        float* __restrict__ wsw) {
  __shared__ __align__(16) char smem[K_SZ];
  char*  xaz  = smem + K_XA;
  float* hn2z = (float*)(smem + K_HN);
  int*   idxz = (int*)(smem + K_IDX);
  float* redz = (float*)(smem + K_RED);
  float* qld2 = (float*)smem;             // phase-B overlay [64 d][68 rows]

  const int t    = threadIdx.x;           // 0..127
  const int bid  = blockIdx.x;            // 0..2047
  const int bimg = bid >> 6;
  const int hw0  = (bid & 63) << 6;       // 64-row hw tile
  const float4*  xb4 = (const float4*)(x + (bimg << 18) + hw0);
  const float4*  cb4 = (const float4*)cb;
  const bf16x8*  cbb = (const bf16x8*)(wsr + WS_CBF);   // fragment-linear

  // ---- stage X tile: bf16 [row][d] swizzled (trunc pack) + sum x^2 ----
  float xsq = 0.f;
  {
    const int p  = t >> 2;                // d-pair 0..31
    const int r0 = (t & 3) << 4;          // row group of 16
    #pragma unroll
    for (int j = 0; j < 4; ++j) {
      float4 A0 = xb4[((2 * p) << 10) + (r0 >> 2) + j];
      float4 A1 = xb4[((2 * p + 1) << 10) + (r0 >> 2) + j];
      const float* a0 = (const float*)&A0;
      const float* a1 = (const float*)&A1;
      #pragma unroll
      for (int u = 0; u < 4; ++u) {
        xsq = fmaf(a0[u], a0[u], xsq);
        xsq = fmaf(a1[u], a1[u], xsq);
        int r = r0 + (j << 2) + u;
        *(unsigned*)(xaz + r * 128 + ((p << 2) ^ swz(r))) = PACKTR(a0[u], a1[u]);
      }
    }
  }
  // ---- hn2 (shifted) from prep ----
  #pragma unroll
  for (int i = 0; i < 4; ++i)
    hn2z[t + (i << 7)] = ((const float*)(wsr + WS_HN2))[t + (i << 7)];
  __syncthreads();

  const int lane = t & 63;
  const int wid  = t >> 6;                // 0..1
  const int lrow = lane & 15;
  const int lk2  = (lane >> 4) << 4;

  // A fragments persist in regs (2 row-subtiles x 2 k-steps)
  bf16x8 af[2][2];
  #pragma unroll
  for (int s = 0; s < 2; ++s) {
    int row = (wid << 5) + (s << 4) + lrow;
    int sw = swz(row);
    af[s][0] = *(const bf16x8*)(xaz + row * 128 + (lk2 ^ sw));
    af[s][1] = *(const bf16x8*)(xaz + row * 128 + ((lk2 ^ 64) ^ sw));
  }

  unsigned bestu[2][4];
  #pragma unroll
  for (int s = 0; s < 2; ++s)
    #pragma unroll
    for (int r = 0; r < 4; ++r) bestu[s][r] = 0u;   // keys are always > 0

  const unsigned tag0 = 511u - (unsigned)lrow;

  // ---- main loop: B direct from L2 (no LDS, no barriers) ----
  #pragma unroll 2
  for (int ct = 0; ct < 32; ++ct) {
    const bf16x8 b0 = cbb[(ct << 7) + lane];        // kk=0 fragment
    const bf16x8 b1 = cbb[(ct << 7) + 64 + lane];   // kk=1 fragment
    const float hv = hn2z[(ct << 4) + lrow];        // 1 - c^2/2 (score shift)
    const unsigned tag = tag0 - (unsigned)(ct << 4);  // 511 - nc
    #pragma unroll
    for (int s = 0; s < 2; ++s) {
      f32x4 acc = {hv, hv, hv, hv};
      acc = __builtin_amdgcn_mfma_f32_16x16x32_bf16(af[s][0], b0, acc, 0, 0, 0);
      acc = __builtin_amdgcn_mfma_f32_16x16x32_bf16(af[s][1], b1, acc, 0, 0, 0);
      #pragma unroll
      for (int r = 0; r < 4; ++r) {
        unsigned key = (__float_as_uint(acc[r]) & 0xFFFFFE00u) | tag;
        bestu[s][r] = max(bestu[s][r], key);
      }
    }
  }

  // ---- cross-lane key-max over the 16 code columns + loss partial ----
  float vsum = 0.f;
  #pragma unroll
  for (int s = 0; s < 2; ++s) {
    #pragma unroll
    for (int r = 0; r < 4; ++r) {
      unsigned k = bestu[s][r];
      #pragma unroll
      for (int m = 1; m <= 8; m <<= 1) {
        unsigned pk = __shfl_xor(k, m, 64);
        k = max(k, pk);
      }
      if (lrow == 0) {
        idxz[(wid << 5) + (s << 4) + ((lane >> 4) << 2) + r] =
            (int)(511u - (k & 511u));
        vsum += __uint_as_float(k & 0xFFFFFE00u) - 1.0f;  // un-shift score
      }
    }
  }
  float lacc = xsq - 2.0f * vsum;
  #pragma unroll
  for (int m = 32; m; m >>= 1) lacc += __shfl_xor(lacc, m, 64);
  if (lane == 0) redz[wid] = lacc;
  __syncthreads();                      // idx+red ready; xa/hn now dead
  if (t == 0) wsw[bid] = redz[0] + redz[1];

  // ---- phase B: gather code rows -> d-major LDS -> float4 NCHW store ----
  {
    const int myrow = t >> 1;           // 0..63
    const int chh   = t & 1;            // d-half
    const int myidx = idxz[myrow];
    const float4* cbr = cb4 + (myidx << 4) + (chh << 3);
    #pragma unroll
    for (int j = 0; j < 8; ++j) {
      float4 v = cbr[j];
      const int d = (chh << 5) + (j << 2);
      qld2[(d + 0) * 68 + myrow] = v.x;
      qld2[(d + 1) * 68 + myrow] = v.y;
      qld2[(d + 2) * 68 + myrow] = v.z;
      qld2[(d + 3) * 68 + myrow] = v.w;
    }
  }
  __syncthreads();
  {
    float* outq = out + 1 + (bimg << 18) + hw0;
    const int r4 = (t & 15) << 2;       // row group of 4 (float4)
    const int d0 = t >> 4;              // base d (0..7)
    #pragma unroll
    for (int i = 0; i < 8; ++i) {
      const int d = d0 + (i << 3);
      float4 v = *(const float4*)(qld2 + d * 68 + r4);    // linear b128
      *(float4*)(outq + (d << 12) + r4) = v;              // coalesced 16B
    }
  }
}

__global__ void vq_finalize(const float* __restrict__ ws, float* __restrict__ out) {
  int t = threadIdx.x;
  __shared__ float red[4];
  float v = 0.f;
  #pragma unroll
  for (int k = 0; k < 8; ++k) v += ws[t + (k << 8)];
  #pragma unroll
  for (int m = 32; m; m >>= 1) v += __shfl_xor(v, m, 64);
  if ((t & 63) == 0) red[t >> 6] = v;
  __syncthreads();
  if (t == 0) out[0] = (red[0] + red[1] + red[2] + red[3]) * (1.25f / 8388608.0f);
}

extern "C" void kernel_launch(void* const* d_in, const int* in_sizes, int n_in,
                              void* d_out, int out_size, void* d_ws, size_t ws_size,
                              hipStream_t stream) {
  const float* x  = (const float*)d_in[0];   // 32*64*64*64 fp32 NCHW
  const float* cb = (const float*)d_in[1];   // 512*64 fp32
  float* out = (float*)d_out;                // [0]=loss, [1..]=quantized NCHW
  char*  ws  = (char*)d_ws;                  // ~76 KB used
  vq_prep<<<8, 64, 0, stream>>>(cb, ws);
  vq_main<<<2048, 128, 0, stream>>>(x, cb, ws, out, (float*)(ws + WS_RED));
  vq_finalize<<<1, 256, 0, stream>>>((float*)(ws + WS_RED), out);
}